// Round 13
// baseline (125.614 us; speedup 1.0000x reference)
//
#include <hip/hip_runtime.h>
#include <hip/hip_bf16.h>
#include <hip/hip_fp16.h>

// Shapes (fixed by the reference)
#define BB   4
#define NN   2048
#define FIN  128
#define HD   256
#define NH   4
#define DK   64
#define NEGV (-1000000000.0f)
#define LOG2E 1.4426950408889634f

typedef _Float16 f16x8 __attribute__((ext_vector_type(8)));
typedef float    f32x16 __attribute__((ext_vector_type(16)));
typedef unsigned long long u64;

// XOR swizzles: flip byte bits 4-6 with row bits (pitch 512B / 256B)
__device__ __forceinline__ int SWZ9(int b){ return b ^ (((b >> 9) & 7) << 4); }
__device__ __forceinline__ int SWZ8(int b){ return b ^ (((b >> 8) & 7) << 4); }

__device__ __forceinline__ float fexp2(float x){
#if __has_builtin(__builtin_amdgcn_exp2f)
  return __builtin_amdgcn_exp2f(x);
#else
  return __exp2f(x);
#endif
}

__device__ __forceinline__ f16x8 pack8(float4 a, float4 b){
  f16x8 r;
  r[0]=(_Float16)a.x; r[1]=(_Float16)a.y; r[2]=(_Float16)a.z; r[3]=(_Float16)a.w;
  r[4]=(_Float16)b.x; r[5]=(_Float16)b.y; r[6]=(_Float16)b.z; r[7]=(_Float16)b.w;
  return r;
}

// ---------------------------------------------------------------------------
// K_setup: blocks [0,2048): int4-wide bitmask pack (maskT[b][mt][n]).
//          blocks [2048,2056): WTF fragment-ordered head weights + aS.
//          blocks [2056,2064): WpF fragment-ordered proj weights.
__global__ void __launch_bounds__(256) k_setup(const int* __restrict__ adj,
                                               const float* __restrict__ Wp,
                                               const float* __restrict__ W1,
                                               const float* __restrict__ a1,
                                               const float* __restrict__ W2,
                                               const float* __restrict__ a2,
                                               u64* __restrict__ maskT,
                                               _Float16* __restrict__ WTF,
                                               _Float16* __restrict__ WpF,
                                               float* __restrict__ aS){
  int bid = blockIdx.x;
  int t = threadIdx.x;
  if (bid < 2048){
    int w = t >> 6, lane = t & 63;
    int row = bid*4 + w;
    int b = row >> 11, n = row & (NN-1);
    const int4* ar = (const int4*)(adj + (size_t)row*NN);
    int g = lane >> 4, q = lane & 15;
    #pragma unroll 2
    for (int step = 0; step < 8; ++step){
      int4 v = ar[step*64 + lane];
      unsigned nib = (unsigned)((v.x!=0) | ((v.y!=0)<<1) | ((v.z!=0)<<2) | ((v.w!=0)<<3));
      unsigned lo = (q < 8) ? (nib << (q*4)) : 0u;
      unsigned hi = (q < 8) ? 0u : (nib << ((q-8)*4));
      #pragma unroll
      for (int off = 1; off < 16; off <<= 1){
        lo |= __shfl_xor(lo, off);
        hi |= __shfl_xor(hi, off);
      }
      if (q == 0) maskT[(size_t)(b*32 + step*4 + g)*NN + n] = ((u64)hi << 32) | lo;
    }
  } else if (bid < 2056){
    int qq = bid - 2048;            // lay*4+hh
    int lay = qq >> 2, hh = qq & 3;
    const float* W = (lay ? W2 : W1) + (size_t)hh*HD*DK;
    const float* a = (lay ? a2 : a1) + (size_t)hh*2*DK;
    _Float16* wf = WTF + (size_t)qq*32*512;     // 32 frags x 512 f16
    int j = t*2;
    int l5 = j >> 4, lh = (j >> 3) & 1, e = j & 7;
    #pragma unroll 4
    for (int f = 0; f < 32; ++f){
      int kk = f >> 1, dh = f & 1;
      wf[f*512 + j]     = (_Float16)W[(kk*16 + lh*8 + e    )*DK + dh*32 + l5];
      wf[f*512 + j + 1] = (_Float16)W[(kk*16 + lh*8 + e + 1)*DK + dh*32 + l5];
    }
    if (t < 128) aS[(size_t)qq*128 + t] = a[t] * LOG2E;
  } else {
    int kk = bid - 2056;            // 0..7 (k-step)
    int j = t*2;
    int l5 = j >> 4, lh = (j >> 3) & 1, e = j & 7;
    #pragma unroll 4
    for (int cs = 0; cs < 8; ++cs){
      WpF[(kk*8 + cs)*512 + j]     = (_Float16)Wp[(kk*16 + lh*8 + e    )*HD + cs*32 + l5];
      WpF[(kk*8 + cs)*512 + j + 1] = (_Float16)Wp[(kk*16 + lh*8 + e + 1)*HD + cs*32 + l5];
    }
  }
}

// ---------------------------------------------------------------------------
// K2: MFMA head projection, proj-fused for layer 1 (unchanged from round 12).
template<int L1>
__global__ void __launch_bounds__(256) k_head4(const float* __restrict__ xin,
                                               const _Float16* __restrict__ WpF,
                                               const _Float16* __restrict__ WTF,
                                               const float* __restrict__ aS,
                                               const float* __restrict__ bp,
                                               float* __restrict__ xout,
                                               _Float16* __restrict__ hT,
                                               float* __restrict__ src,
                                               float* __restrict__ dst){
  int nt = blockIdx.x & 31;
  int bh = blockIdx.x >> 5;
  int b = bh >> 2, hh = bh & 3;
  int n0 = nt * 64;
  int t = threadIdx.x;
  int w = t >> 6, l = t & 63, lh = l >> 5, l5 = l & 31;
  int wr = w >> 1, wc = w & 1;

  __shared__ __align__(16) char sm[50176];  // xs16 [0,32K); nfs [32K,48K); sd [48K,49K)

  if (L1){
    {
      int r = t >> 2, c0 = (t & 3) * 32;
      const float* np = xin + ((size_t)(b*NN) + n0 + r)*FIN + c0;
      #pragma unroll
      for (int u = 0; u < 4; ++u){
        float4 v0 = *(const float4*)&np[u*8];
        float4 v1 = *(const float4*)&np[u*8 + 4];
        *(f16x8*)&sm[32768 + SWZ8(r*256 + (c0 + u*8)*2)] = pack8(v0, v1);
      }
    }
    __syncthreads();
    f32x16 p00 = {}, p01 = {}, p10 = {}, p11 = {};
    #pragma unroll
    for (int kk = 0; kk < 8; ++kk){
      int ab = (kk*16 + lh*8)*2;
      f16x8 A0 = *(const f16x8*)&sm[32768 + SWZ8(l5*256 + ab)];
      f16x8 A1 = *(const f16x8*)&sm[32768 + SWZ8((32 + l5)*256 + ab)];
      const char* bf = (const char*)WpF + (size_t)(kk*8 + w*2)*1024 + l5*32 + lh*16;
      f16x8 B0 = *(const f16x8*)bf;
      f16x8 B1 = *(const f16x8*)(bf + 1024);
      p00 = __builtin_amdgcn_mfma_f32_32x32x16_f16(A0, B0, p00, 0, 0, 0);
      p01 = __builtin_amdgcn_mfma_f32_32x32x16_f16(A0, B1, p01, 0, 0, 0);
      p10 = __builtin_amdgcn_mfma_f32_32x32x16_f16(A1, B0, p10, 0, 0, 0);
      p11 = __builtin_amdgcn_mfma_f32_32x32x16_f16(A1, B1, p11, 0, 0, 0);
    }
    int c0a = w*64 + l5;
    float bp0 = bp[c0a], bp1 = bp[c0a + 32];
    size_t ro = ((size_t)(b*NN) + n0)*HD;
    #pragma unroll
    for (int g = 0; g < 16; ++g){
      int rr = (g & 3) + 8*(g >> 2) + 4*lh;
      float v00 = p00[g] + bp0, v01 = p01[g] + bp1;
      float v10 = p10[g] + bp0, v11 = p11[g] + bp1;
      *(_Float16*)&sm[SWZ9(rr*512 + c0a*2)]             = (_Float16)v00;
      *(_Float16*)&sm[SWZ9(rr*512 + (c0a + 32)*2)]      = (_Float16)v01;
      *(_Float16*)&sm[SWZ9((rr+32)*512 + c0a*2)]        = (_Float16)v10;
      *(_Float16*)&sm[SWZ9((rr+32)*512 + (c0a + 32)*2)] = (_Float16)v11;
      if (hh == 0){
        xout[ro + (size_t)rr*HD + c0a]           = v00;
        xout[ro + (size_t)rr*HD + c0a + 32]      = v01;
        xout[ro + (size_t)(rr+32)*HD + c0a]      = v10;
        xout[ro + (size_t)(rr+32)*HD + c0a + 32] = v11;
      }
    }
    __syncthreads();
  } else {
    int r = t >> 2, ks = (t & 3) * 64;
    const float* xp = &xin[((size_t)(b*NN) + n0 + r)*HD + ks];
    #pragma unroll
    for (int u = 0; u < 8; ++u){
      float4 v0 = *(const float4*)&xp[u*8];
      float4 v1 = *(const float4*)&xp[u*8 + 4];
      *(f16x8*)&sm[SWZ9(r*512 + (ks + u*8)*2)] = pack8(v0, v1);
    }
    __syncthreads();
  }

  // h-MFMA: A = x-tile rows (wr half), B = WTF frags (wc d-half), K=256
  f32x16 hA = {}, hB = {};
  const char* wtb = (const char*)WTF + (size_t)hh*32768 + wc*1024 + l5*32 + lh*16;
  #pragma unroll
  for (int kk = 0; kk < 16; kk += 2){
    int ab0 = (kk*16 + lh*8)*2;
    int ab1 = ((kk+1)*16 + lh*8)*2;
    f16x8 A0 = *(const f16x8*)&sm[SWZ9((wr*32 + l5)*512 + ab0)];
    f16x8 A1 = *(const f16x8*)&sm[SWZ9((wr*32 + l5)*512 + ab1)];
    f16x8 B0 = *(const f16x8*)(wtb + (size_t)kk*2048);
    f16x8 B1 = *(const f16x8*)(wtb + (size_t)(kk+1)*2048);
    hA = __builtin_amdgcn_mfma_f32_32x32x16_f16(A0, B0, hA, 0, 0, 0);
    hB = __builtin_amdgcn_mfma_f32_32x32x16_f16(A1, B1, hB, 0, 0, 0);
  }
  f32x16 acc = hA + hB;

  __syncthreads();   // xs16 dead; overlay ls
  _Float16* ls = (_Float16*)sm;        // [64 d][80 rows pad] f16 = 10240B
  int col = wc*32 + l5;
  float as = aS[(size_t)hh*128 + col];
  float ad = aS[(size_t)hh*128 + 64 + col];
  float* sd = (float*)(sm + 49152);    // [2][2][64] f32
  #pragma unroll
  for (int g = 0; g < 16; ++g){
    int row = wr*32 + (g & 3) + 8*(g >> 2) + 4*lh;
    ls[col*80 + row] = (_Float16)acc[g];
    float sv = acc[g] * as;
    float dv = acc[g] * ad;
    #pragma unroll
    for (int o = 16; o >= 1; o >>= 1){ sv += __shfl_xor(sv, o); dv += __shfl_xor(dv, o); }
    if (l5 == 0){
      sd[wc*64 + row]       = sv;
      sd[128 + wc*64 + row] = dv;
    }
  }
  __syncthreads();
  int dd = t >> 2, part = t & 3;
  f16x8 o0 = *(const f16x8*)&ls[dd*80 + part*16];
  f16x8 o1 = *(const f16x8*)&ls[dd*80 + part*16 + 8];
  int base = part*1024 + (dd >> 5)*512 + (dd & 31)*16;
  _Float16* op = hT + (size_t)bh*131072 + (size_t)nt*4096 + base;
  *(f16x8*)op = o0;
  *(f16x8*)(op + 8) = o1;
  if (t < 64){
    src[bh*NN + n0 + t] = sd[t] + sd[64 + t];
    dst[bh*NN + n0 + t] = sd[128 + t] + sd[192 + t];
  }
}

// ---------------------------------------------------------------------------
// K3: MFMA attention, m-split. Block = 32 rows x 1024 cols (half ms); 4 waves =
// 4 k-chunks. FULLY UNROLLED tile loop: straight-line indexed loads let the
// scheduler software-pipeline mask/B/dq fetches several tiles ahead (round-12's
// manual 1-deep prefetch gave only ~140cyc cover vs ~300-900cyc L2/HBM latency).
__global__ void __launch_bounds__(256, 4) k_attn8(const float* __restrict__ src,
                                                  const float* __restrict__ dst,
                                                  const _Float16* __restrict__ hT,
                                                  const u64* __restrict__ maskT,
                                                  _Float16* __restrict__ accB,
                                                  float* __restrict__ psB){
  int ms = blockIdx.x & 1;
  int rb = (blockIdx.x >> 1) & 63;
  int bh = blockIdx.x >> 7;
  int b  = bh >> 2;
  int n0 = rb * 32;
  int t = threadIdx.x;
  int w = t >> 6, l = t & 63;
  int lh = l >> 5, l5 = l & 31;

  __shared__ __align__(16) char smem[9728];    // dstS 4KB in loop; cs 9.2KB epilogue
  __shared__ float rs[4][32];
  __shared__ float red[4];
  float* dstS = (float*)smem;
  float* cs   = (float*)smem;

  {
    const float* dp = dst + bh*NN;
    float4 a = *(const float4*)&dp[t*4];
    float4 bq = *(const float4*)&dp[1024 + t*4];
    float mloc = fmaxf(fmaxf(fmaxf(a.x,a.y), fmaxf(a.z,a.w)),
                       fmaxf(fmaxf(bq.x,bq.y), fmaxf(bq.z,bq.w)));
    *(float4*)&dstS[t*4] = ms ? bq : a;
    #pragma unroll
    for (int o = 32; o >= 1; o >>= 1) mloc = fmaxf(mloc, __shfl_xor(mloc, o));
    if (l == 0) red[w] = mloc;
  }
  __syncthreads();
  float Mbh = fmaxf(fmaxf(red[0], red[1]), fmaxf(red[2], red[3]));
  float srcv = src[bh*NN + n0 + l5];
  float bv = srcv + Mbh;
  float bnd = fmaxf(bv, 0.2f*bv);
  float2 ps2 = make_float2(0.f, 0.f);
  f32x16 acc0 = {}, acc1 = {};

  int kb = w*16 + lh*8;
  const u64* mp = maskT + (size_t)(b*32 + ms*16)*NN + n0 + l5;
  const char* gB0 = (const char*)hT + (size_t)bh*262144 + ms*131072
                    + w*2048 + l5*32 + lh*16;

  #pragma unroll
  for (int mt = 0; mt < 16; ++mt){
    u64 mk = mp[(size_t)mt*NN];
    f16x8 B0 = *(const f16x8*)(gB0 + (size_t)mt*8192);
    f16x8 B1 = *(const f16x8*)(gB0 + (size_t)mt*8192 + 1024);
    float4 dq0 = *(const float4*)&dstS[mt*64 + kb];
    float4 dq1 = *(const float4*)&dstS[mt*64 + kb + 4];
    unsigned bits = (unsigned)(mk >> kb) & 0xFFu;
    float dvals[8] = {dq0.x,dq0.y,dq0.z,dq0.w,dq1.x,dq1.y,dq1.z,dq1.w};
    f16x8 A;
    float p0s = 0.f, p1s = 0.f;
    #pragma unroll
    for (int i = 0; i < 8; i += 2){
      float e0 = srcv + dvals[i];
      float e1 = srcv + dvals[i+1];
      e0 = fmaxf(e0, 0.2f*e0);           // leaky (log2-scaled domain)
      e1 = fmaxf(e1, 0.2f*e1);
      e0 = ((bits >> i) & 1u) ? e0 : NEGV;
      e1 = ((bits >> (i+1)) & 1u) ? e1 : NEGV;
      float p0 = fexp2(e0 - bnd);
      float p1 = fexp2(e1 - bnd);
      p0s += p0; p1s += p1;
      A[i]   = (_Float16)p0;
      A[i+1] = (_Float16)p1;
    }
    ps2.x += p0s; ps2.y += p1s;
    acc0 = __builtin_amdgcn_mfma_f32_32x32x16_f16(A, B0, acc0, 0, 0, 0);
    acc1 = __builtin_amdgcn_mfma_f32_32x32x16_f16(A, B1, acc1, 0, 0, 0);
  }

  float psum = ps2.x + ps2.y;
  psum += __shfl_xor(psum, 32);
  if (l < 32) rs[w][l5] = psum;
  __syncthreads();                       // dstS dead; cs overlay safe
  _Float16* accO = accB + (size_t)ms*2097152;
  float* psO  = psB + (size_t)ms*32768;
  if (t < 32) psO[bh*NN + n0 + t] = rs[0][t] + rs[1][t] + rs[2][t] + rs[3][t];
  // sequential cross-wave combine (fits 9.2KB: 64 lanes x 36 floats)
  #pragma unroll 1
  for (int ww = 1; ww < 4; ++ww){
    if (w == ww){
      float* base = cs + l*36;
      *(f32x16*)(base)      = acc0;
      *(f32x16*)(base + 16) = acc1;
    }
    __syncthreads();
    if (w == 0){
      const float* base = cs + l*36;
      acc0 += *(const f32x16*)(base);
      acc1 += *(const f32x16*)(base + 16);
    }
    __syncthreads();
  }
  if (w == 0){
    #pragma unroll
    for (int g = 0; g < 16; ++g){
      int row = (g & 3) + 8*(g >> 2) + 4*lh;
      size_t o = ((size_t)bh*NN + n0 + row)*DK;
      accO[o + l5]      = (_Float16)acc0[g];
      accO[o + 32 + l5] = (_Float16)acc1[g];
    }
  }
}

// ---------------------------------------------------------------------------
// K4: x[b,j,:] += elu(LN(x1[b,j,:])); normalization folded in.
__global__ void __launch_bounds__(256) k_ln1(const _Float16* __restrict__ a0,
                                             const _Float16* __restrict__ a1,
                                             const float* __restrict__ p0,
                                             const float* __restrict__ p1,
                                             const float* __restrict__ sc,
                                             const float* __restrict__ bi,
                                             float* __restrict__ x){
  int j = blockIdx.x & (NN-1);
  int b = blockIdx.x / NN;
  int c = threadIdx.x;
  int w = c >> 6, l = c & 63;
  int hh = j >> 9;
  int node = ((j & 511) << 2) + w;
  size_t ridx = (size_t)(b*NH + hh)*NN + node;
  float inv = 1.f / (p0[ridx] + p1[ridx]);
  size_t idx = ridx*DK + l;
  float v = ((float)a0[idx] + (float)a1[idx]) * inv;
  __shared__ float red[8];
  float s = v;
  #pragma unroll
  for (int o = 32; o >= 1; o >>= 1) s += __shfl_xor(s, o);
  if (l == 0) red[w] = s;
  __syncthreads();
  float mu = (red[0]+red[1]+red[2]+red[3]) * (1.f/HD);
  float dv = v - mu;
  float q = dv*dv;
  #pragma unroll
  for (int o = 32; o >= 1; o >>= 1) q += __shfl_xor(q, o);
  if (l == 0) red[4+w] = q;
  __syncthreads();
  float var = (red[4]+red[5]+red[6]+red[7]) * (1.f/HD);
  float ln = dv * rsqrtf(var + 1e-5f) * sc[c] + bi[c];
  float el = (ln > 0.f) ? ln : (__expf(ln) - 1.f);
  x[(size_t)blockIdx.x*HD + c] += el;
}

// ---------------------------------------------------------------------------
// K5: out[b,n,d] = LN_64( mean_h att2[b,h,n,d] ), normalization folded in
__global__ void __launch_bounds__(256) k_final(const _Float16* __restrict__ a0,
                                               const _Float16* __restrict__ a1,
                                               const float* __restrict__ p0,
                                               const float* __restrict__ p1,
                                               const float* __restrict__ sc,
                                               const float* __restrict__ bi,
                                               float* __restrict__ out){
  int w = threadIdx.x >> 6; int d = threadIdx.x & 63;
  int bn = blockIdx.x*4 + w;
  int b = bn / NN; int n = bn & (NN-1);
  float v = 0.f;
  #pragma unroll
  for (int hh = 0; hh < NH; ++hh){
    size_t ridx = (size_t)(b*NH + hh)*NN + n;
    float inv = 1.f / (p0[ridx] + p1[ridx]);
    size_t idx = ridx*DK + d;
    v += ((float)a0[idx] + (float)a1[idx]) * inv;
  }
  v *= 0.25f;
  float s = v;
  #pragma unroll
  for (int o = 32; o >= 1; o >>= 1) s += __shfl_xor(s, o);
  float mu = s * (1.f/DK);
  float dv = v - mu;
  float q = dv*dv;
  #pragma unroll
  for (int o = 32; o >= 1; o >>= 1) q += __shfl_xor(q, o);
  float var = q * (1.f/DK);
  float ln = dv * rsqrtf(var + 1e-5f) * sc[d] + bi[d];
  out[(size_t)bn*DK + d] = ln;
}

// ---------------------------------------------------------------------------
extern "C" void kernel_launch(void* const* d_in, const int* in_sizes, int n_in,
                              void* d_out, int out_size, void* d_ws, size_t ws_size,
                              hipStream_t stream){
  const float* nf   = (const float*)d_in[0];
  const int*   adj  = (const int*)d_in[1];
  const float* Wp   = (const float*)d_in[2];
  const float* bp   = (const float*)d_in[3];
  const float* W1   = (const float*)d_in[4];
  const float* a1   = (const float*)d_in[5];
  const float* ln1s = (const float*)d_in[6];
  const float* ln1b = (const float*)d_in[7];
  const float* W2   = (const float*)d_in[8];
  const float* a2   = (const float*)d_in[9];
  const float* ln2s = (const float*)d_in[10];
  const float* ln2b = (const float*)d_in[11];

  float* ws   = (float*)d_ws;
  float* x    = ws;                            // 2,097,152 f32
  _Float16* accF = (_Float16*)(ws + 2097152);  // 2 x 2,097,152 f16
  float* srcb = ws + 3*2097152;                // 32,768
  float* dstb = srcb + 32768;                  // 32,768
  float* psA  = dstb + 32768;                  // 2 x 32,768
  _Float16* hT = (_Float16*)(psA + 2*32768);   // 2,097,152 f16
  u64* maskT  = (u64*)(hT + 2097152);          // 262,144 u64
  _Float16* WTF = (_Float16*)(maskT + 262144); // 131,072 f16 (2 layers)
  _Float16* WpF = WTF + 131072;                // 32,768 f16
  float* aS   = (float*)(WpF + 32768);         // 1024 f32

  _Float16* accH0 = accF;
  _Float16* accH1 = accF + 2097152;
  float* psH0  = psA;
  float* psH1  = psA + 32768;

  k_setup   <<<2064,        256, 0, stream>>>(adj, Wp, W1, a1, W2, a2,
                                              maskT, WTF, WpF, aS);
  k_head4<1><<<BB*NH*NN/64, 256, 0, stream>>>(nf, WpF, WTF,        aS,       bp, x, hT, srcb, dstb);
  k_attn8   <<<BB*NH*NN/16, 256, 0, stream>>>(srcb, dstb, hT, maskT, accF, psA);
  k_ln1     <<<BB*NN,       256, 0, stream>>>(accH0, accH1, psH0, psH1, ln1s, ln1b, x);
  k_head4<0><<<BB*NH*NN/64, 256, 0, stream>>>(x, WpF, WTF + 65536, aS + 512, bp, x, hT, srcb, dstb);
  k_attn8   <<<BB*NH*NN/16, 256, 0, stream>>>(srcb, dstb, hT, maskT, accF, psA);
  k_final   <<<BB*NN/4,     256, 0, stream>>>(accH0, accH1, psH0, psH1, ln2s, ln2b, (float*)d_out);
}

// Round 14
// 120.361 us; speedup vs baseline: 1.0436x; 1.0436x over previous
//
#include <hip/hip_runtime.h>
#include <hip/hip_bf16.h>
#include <hip/hip_fp16.h>

// Shapes (fixed by the reference)
#define BB   4
#define NN   2048
#define FIN  128
#define HD   256
#define NH   4
#define DK   64
#define NEGV (-1000000000.0f)
#define LOG2E 1.4426950408889634f

typedef _Float16 f16x8 __attribute__((ext_vector_type(8)));
typedef float    f32x16 __attribute__((ext_vector_type(16)));
typedef unsigned long long u64;

// XOR swizzles: flip byte bits 4-6 with row bits (pitch 512B / 256B)
__device__ __forceinline__ int SWZ9(int b){ return b ^ (((b >> 9) & 7) << 4); }
__device__ __forceinline__ int SWZ8(int b){ return b ^ (((b >> 8) & 7) << 4); }

__device__ __forceinline__ float fexp2(float x){
#if __has_builtin(__builtin_amdgcn_exp2f)
  return __builtin_amdgcn_exp2f(x);
#else
  return __exp2f(x);
#endif
}

__device__ __forceinline__ f16x8 pack8(float4 a, float4 b){
  f16x8 r;
  r[0]=(_Float16)a.x; r[1]=(_Float16)a.y; r[2]=(_Float16)a.z; r[3]=(_Float16)a.w;
  r[4]=(_Float16)b.x; r[5]=(_Float16)b.y; r[6]=(_Float16)b.z; r[7]=(_Float16)b.w;
  return r;
}

// ---------------------------------------------------------------------------
// K_setup: blocks [0,2048): int4-wide bitmask pack (maskT[b][mt][n]).
//          blocks [2048,2056): WTF fragment-ordered head weights + aS.
//          blocks [2056,2064): WpF fragment-ordered proj weights.
__global__ void __launch_bounds__(256) k_setup(const int* __restrict__ adj,
                                               const float* __restrict__ Wp,
                                               const float* __restrict__ W1,
                                               const float* __restrict__ a1,
                                               const float* __restrict__ W2,
                                               const float* __restrict__ a2,
                                               u64* __restrict__ maskT,
                                               _Float16* __restrict__ WTF,
                                               _Float16* __restrict__ WpF,
                                               float* __restrict__ aS){
  int bid = blockIdx.x;
  int t = threadIdx.x;
  if (bid < 2048){
    int w = t >> 6, lane = t & 63;
    int row = bid*4 + w;
    int b = row >> 11, n = row & (NN-1);
    const int4* ar = (const int4*)(adj + (size_t)row*NN);
    int g = lane >> 4, q = lane & 15;
    #pragma unroll 2
    for (int step = 0; step < 8; ++step){
      int4 v = ar[step*64 + lane];
      unsigned nib = (unsigned)((v.x!=0) | ((v.y!=0)<<1) | ((v.z!=0)<<2) | ((v.w!=0)<<3));
      unsigned lo = (q < 8) ? (nib << (q*4)) : 0u;
      unsigned hi = (q < 8) ? 0u : (nib << ((q-8)*4));
      #pragma unroll
      for (int off = 1; off < 16; off <<= 1){
        lo |= __shfl_xor(lo, off);
        hi |= __shfl_xor(hi, off);
      }
      if (q == 0) maskT[(size_t)(b*32 + step*4 + g)*NN + n] = ((u64)hi << 32) | lo;
    }
  } else if (bid < 2056){
    int qq = bid - 2048;            // lay*4+hh
    int lay = qq >> 2, hh = qq & 3;
    const float* W = (lay ? W2 : W1) + (size_t)hh*HD*DK;
    const float* a = (lay ? a2 : a1) + (size_t)hh*2*DK;
    _Float16* wf = WTF + (size_t)qq*32*512;     // 32 frags x 512 f16
    int j = t*2;
    int l5 = j >> 4, lh = (j >> 3) & 1, e = j & 7;
    #pragma unroll 4
    for (int f = 0; f < 32; ++f){
      int kk = f >> 1, dh = f & 1;
      wf[f*512 + j]     = (_Float16)W[(kk*16 + lh*8 + e    )*DK + dh*32 + l5];
      wf[f*512 + j + 1] = (_Float16)W[(kk*16 + lh*8 + e + 1)*DK + dh*32 + l5];
    }
    if (t < 128) aS[(size_t)qq*128 + t] = a[t] * LOG2E;
  } else {
    int kk = bid - 2056;            // 0..7 (k-step)
    int j = t*2;
    int l5 = j >> 4, lh = (j >> 3) & 1, e = j & 7;
    #pragma unroll 4
    for (int cs = 0; cs < 8; ++cs){
      WpF[(kk*8 + cs)*512 + j]     = (_Float16)Wp[(kk*16 + lh*8 + e    )*HD + cs*32 + l5];
      WpF[(kk*8 + cs)*512 + j + 1] = (_Float16)Wp[(kk*16 + lh*8 + e + 1)*HD + cs*32 + l5];
    }
  }
}

// ---------------------------------------------------------------------------
// K2: MFMA head projection, proj-fused for layer 1 (unchanged from round 12).
template<int L1>
__global__ void __launch_bounds__(256) k_head4(const float* __restrict__ xin,
                                               const _Float16* __restrict__ WpF,
                                               const _Float16* __restrict__ WTF,
                                               const float* __restrict__ aS,
                                               const float* __restrict__ bp,
                                               float* __restrict__ xout,
                                               _Float16* __restrict__ hT,
                                               float* __restrict__ src,
                                               float* __restrict__ dst){
  int nt = blockIdx.x & 31;
  int bh = blockIdx.x >> 5;
  int b = bh >> 2, hh = bh & 3;
  int n0 = nt * 64;
  int t = threadIdx.x;
  int w = t >> 6, l = t & 63, lh = l >> 5, l5 = l & 31;
  int wr = w >> 1, wc = w & 1;

  __shared__ __align__(16) char sm[50176];  // xs16 [0,32K); nfs [32K,48K); sd [48K,49K)

  if (L1){
    {
      int r = t >> 2, c0 = (t & 3) * 32;
      const float* np = xin + ((size_t)(b*NN) + n0 + r)*FIN + c0;
      #pragma unroll
      for (int u = 0; u < 4; ++u){
        float4 v0 = *(const float4*)&np[u*8];
        float4 v1 = *(const float4*)&np[u*8 + 4];
        *(f16x8*)&sm[32768 + SWZ8(r*256 + (c0 + u*8)*2)] = pack8(v0, v1);
      }
    }
    __syncthreads();
    f32x16 p00 = {}, p01 = {}, p10 = {}, p11 = {};
    #pragma unroll
    for (int kk = 0; kk < 8; ++kk){
      int ab = (kk*16 + lh*8)*2;
      f16x8 A0 = *(const f16x8*)&sm[32768 + SWZ8(l5*256 + ab)];
      f16x8 A1 = *(const f16x8*)&sm[32768 + SWZ8((32 + l5)*256 + ab)];
      const char* bf = (const char*)WpF + (size_t)(kk*8 + w*2)*1024 + l5*32 + lh*16;
      f16x8 B0 = *(const f16x8*)bf;
      f16x8 B1 = *(const f16x8*)(bf + 1024);
      p00 = __builtin_amdgcn_mfma_f32_32x32x16_f16(A0, B0, p00, 0, 0, 0);
      p01 = __builtin_amdgcn_mfma_f32_32x32x16_f16(A0, B1, p01, 0, 0, 0);
      p10 = __builtin_amdgcn_mfma_f32_32x32x16_f16(A1, B0, p10, 0, 0, 0);
      p11 = __builtin_amdgcn_mfma_f32_32x32x16_f16(A1, B1, p11, 0, 0, 0);
    }
    int c0a = w*64 + l5;
    float bp0 = bp[c0a], bp1 = bp[c0a + 32];
    size_t ro = ((size_t)(b*NN) + n0)*HD;
    #pragma unroll
    for (int g = 0; g < 16; ++g){
      int rr = (g & 3) + 8*(g >> 2) + 4*lh;
      float v00 = p00[g] + bp0, v01 = p01[g] + bp1;
      float v10 = p10[g] + bp0, v11 = p11[g] + bp1;
      *(_Float16*)&sm[SWZ9(rr*512 + c0a*2)]             = (_Float16)v00;
      *(_Float16*)&sm[SWZ9(rr*512 + (c0a + 32)*2)]      = (_Float16)v01;
      *(_Float16*)&sm[SWZ9((rr+32)*512 + c0a*2)]        = (_Float16)v10;
      *(_Float16*)&sm[SWZ9((rr+32)*512 + (c0a + 32)*2)] = (_Float16)v11;
      if (hh == 0){
        xout[ro + (size_t)rr*HD + c0a]           = v00;
        xout[ro + (size_t)rr*HD + c0a + 32]      = v01;
        xout[ro + (size_t)(rr+32)*HD + c0a]      = v10;
        xout[ro + (size_t)(rr+32)*HD + c0a + 32] = v11;
      }
    }
    __syncthreads();
  } else {
    int r = t >> 2, ks = (t & 3) * 64;
    const float* xp = &xin[((size_t)(b*NN) + n0 + r)*HD + ks];
    #pragma unroll
    for (int u = 0; u < 8; ++u){
      float4 v0 = *(const float4*)&xp[u*8];
      float4 v1 = *(const float4*)&xp[u*8 + 4];
      *(f16x8*)&sm[SWZ9(r*512 + (ks + u*8)*2)] = pack8(v0, v1);
    }
    __syncthreads();
  }

  // h-MFMA: A = x-tile rows (wr half), B = WTF frags (wc d-half), K=256
  f32x16 hA = {}, hB = {};
  const char* wtb = (const char*)WTF + (size_t)hh*32768 + wc*1024 + l5*32 + lh*16;
  #pragma unroll
  for (int kk = 0; kk < 16; kk += 2){
    int ab0 = (kk*16 + lh*8)*2;
    int ab1 = ((kk+1)*16 + lh*8)*2;
    f16x8 A0 = *(const f16x8*)&sm[SWZ9((wr*32 + l5)*512 + ab0)];
    f16x8 A1 = *(const f16x8*)&sm[SWZ9((wr*32 + l5)*512 + ab1)];
    f16x8 B0 = *(const f16x8*)(wtb + (size_t)kk*2048);
    f16x8 B1 = *(const f16x8*)(wtb + (size_t)(kk+1)*2048);
    hA = __builtin_amdgcn_mfma_f32_32x32x16_f16(A0, B0, hA, 0, 0, 0);
    hB = __builtin_amdgcn_mfma_f32_32x32x16_f16(A1, B1, hB, 0, 0, 0);
  }
  f32x16 acc = hA + hB;

  __syncthreads();   // xs16 dead; overlay ls
  _Float16* ls = (_Float16*)sm;        // [64 d][80 rows pad] f16 = 10240B
  int col = wc*32 + l5;
  float as = aS[(size_t)hh*128 + col];
  float ad = aS[(size_t)hh*128 + 64 + col];
  float* sd = (float*)(sm + 49152);    // [2][2][64] f32
  #pragma unroll
  for (int g = 0; g < 16; ++g){
    int row = wr*32 + (g & 3) + 8*(g >> 2) + 4*lh;
    ls[col*80 + row] = (_Float16)acc[g];
    float sv = acc[g] * as;
    float dv = acc[g] * ad;
    #pragma unroll
    for (int o = 16; o >= 1; o >>= 1){ sv += __shfl_xor(sv, o); dv += __shfl_xor(dv, o); }
    if (l5 == 0){
      sd[wc*64 + row]       = sv;
      sd[128 + wc*64 + row] = dv;
    }
  }
  __syncthreads();
  int dd = t >> 2, part = t & 3;
  f16x8 o0 = *(const f16x8*)&ls[dd*80 + part*16];
  f16x8 o1 = *(const f16x8*)&ls[dd*80 + part*16 + 8];
  int base = part*1024 + (dd >> 5)*512 + (dd & 31)*16;
  _Float16* op = hT + (size_t)bh*131072 + (size_t)nt*4096 + base;
  *(f16x8*)op = o0;
  *(f16x8*)(op + 8) = o1;
  if (t < 64){
    src[bh*NN + n0 + t] = sd[t] + sd[64 + t];
    dst[bh*NN + n0 + t] = sd[128 + t] + sd[192 + t];
  }
}

// ---------------------------------------------------------------------------
// K3: MFMA attention, m-split. Block = 32 rows x 1024 cols (half ms); 4 waves =
// 4 k-chunks. EXPLICIT 2-DEEP prefetch slots for the global streams (mask, B):
// round-13 lesson — the scheduler won't hoist use-point loads into a pipeline;
// textual order must carry the prefetch distance. dq stays an in-loop LDS read.
__global__ void __launch_bounds__(256, 4) k_attn8(const float* __restrict__ src,
                                                  const float* __restrict__ dst,
                                                  const _Float16* __restrict__ hT,
                                                  const u64* __restrict__ maskT,
                                                  _Float16* __restrict__ accB,
                                                  float* __restrict__ psB){
  int ms = blockIdx.x & 1;
  int rb = (blockIdx.x >> 1) & 63;
  int bh = blockIdx.x >> 7;
  int b  = bh >> 2;
  int n0 = rb * 32;
  int t = threadIdx.x;
  int w = t >> 6, l = t & 63;
  int lh = l >> 5, l5 = l & 31;

  __shared__ __align__(16) char smem[9728];    // dstS 4KB in loop; cs 9.2KB epilogue
  __shared__ float rs[4][32];
  __shared__ float red[4];
  float* dstS = (float*)smem;
  float* cs   = (float*)smem;

  {
    const float* dp = dst + bh*NN;
    float4 a = *(const float4*)&dp[t*4];
    float4 bq = *(const float4*)&dp[1024 + t*4];
    float mloc = fmaxf(fmaxf(fmaxf(a.x,a.y), fmaxf(a.z,a.w)),
                       fmaxf(fmaxf(bq.x,bq.y), fmaxf(bq.z,bq.w)));
    *(float4*)&dstS[t*4] = ms ? bq : a;
    #pragma unroll
    for (int o = 32; o >= 1; o >>= 1) mloc = fmaxf(mloc, __shfl_xor(mloc, o));
    if (l == 0) red[w] = mloc;
  }
  __syncthreads();
  float Mbh = fmaxf(fmaxf(red[0], red[1]), fmaxf(red[2], red[3]));
  float srcv = src[bh*NN + n0 + l5];
  float bv = srcv + Mbh;
  float bnd = fmaxf(bv, 0.2f*bv);
  float2 ps2 = make_float2(0.f, 0.f);
  f32x16 acc0 = {}, acc1 = {};

  int kb = w*16 + lh*8;
  const u64* mp = maskT + (size_t)(b*32 + ms*16)*NN + n0 + l5;
  const char* gB0 = (const char*)hT + (size_t)bh*262144 + ms*131072
                    + w*2048 + l5*32 + lh*16;

  // 2-deep prefetch slots (rotation resolved statically by full unroll)
  u64 mkS0 = mp[0];
  f16x8 B0S0 = *(const f16x8*)(gB0);
  f16x8 B1S0 = *(const f16x8*)(gB0 + 1024);
  u64 mkS1 = mp[NN];
  f16x8 B0S1 = *(const f16x8*)(gB0 + 8192);
  f16x8 B1S1 = *(const f16x8*)(gB0 + 8192 + 1024);

  #pragma unroll
  for (int mt = 0; mt < 16; ++mt){
    // consume slot 0
    u64 mkC = mkS0;
    f16x8 B0C = B0S0, B1C = B1S0;
    // shift slot 1 -> 0, refill slot 1 with tile mt+2
    mkS0 = mkS1; B0S0 = B0S1; B1S0 = B1S1;
    if (mt < 14){
      mkS1 = mp[(size_t)(mt+2)*NN];
      B0S1 = *(const f16x8*)(gB0 + (size_t)(mt+2)*8192);
      B1S1 = *(const f16x8*)(gB0 + (size_t)(mt+2)*8192 + 1024);
    }
    float4 dq0 = *(const float4*)&dstS[mt*64 + kb];
    float4 dq1 = *(const float4*)&dstS[mt*64 + kb + 4];
    unsigned bits = (unsigned)(mkC >> kb) & 0xFFu;
    float dvals[8] = {dq0.x,dq0.y,dq0.z,dq0.w,dq1.x,dq1.y,dq1.z,dq1.w};
    f16x8 A;
    float p0s = 0.f, p1s = 0.f;
    #pragma unroll
    for (int i = 0; i < 8; i += 2){
      float e0 = srcv + dvals[i];
      float e1 = srcv + dvals[i+1];
      e0 = fmaxf(e0, 0.2f*e0);           // leaky (log2-scaled domain)
      e1 = fmaxf(e1, 0.2f*e1);
      e0 = ((bits >> i) & 1u) ? e0 : NEGV;
      e1 = ((bits >> (i+1)) & 1u) ? e1 : NEGV;
      float p0 = fexp2(e0 - bnd);
      float p1 = fexp2(e1 - bnd);
      p0s += p0; p1s += p1;
      A[i]   = (_Float16)p0;
      A[i+1] = (_Float16)p1;
    }
    ps2.x += p0s; ps2.y += p1s;
    acc0 = __builtin_amdgcn_mfma_f32_32x32x16_f16(A, B0C, acc0, 0, 0, 0);
    acc1 = __builtin_amdgcn_mfma_f32_32x32x16_f16(A, B1C, acc1, 0, 0, 0);
  }

  float psum = ps2.x + ps2.y;
  psum += __shfl_xor(psum, 32);
  if (l < 32) rs[w][l5] = psum;
  __syncthreads();                       // dstS dead; cs overlay safe
  _Float16* accO = accB + (size_t)ms*2097152;
  float* psO  = psB + (size_t)ms*32768;
  if (t < 32) psO[bh*NN + n0 + t] = rs[0][t] + rs[1][t] + rs[2][t] + rs[3][t];
  // sequential cross-wave combine (fits 9.2KB: 64 lanes x 36 floats)
  #pragma unroll 1
  for (int ww = 1; ww < 4; ++ww){
    if (w == ww){
      float* base = cs + l*36;
      *(f32x16*)(base)      = acc0;
      *(f32x16*)(base + 16) = acc1;
    }
    __syncthreads();
    if (w == 0){
      const float* base = cs + l*36;
      acc0 += *(const f32x16*)(base);
      acc1 += *(const f32x16*)(base + 16);
    }
    __syncthreads();
  }
  if (w == 0){
    #pragma unroll
    for (int g = 0; g < 16; ++g){
      int row = (g & 3) + 8*(g >> 2) + 4*lh;
      size_t o = ((size_t)bh*NN + n0 + row)*DK;
      accO[o + l5]      = (_Float16)acc0[g];
      accO[o + 32 + l5] = (_Float16)acc1[g];
    }
  }
}

// ---------------------------------------------------------------------------
// K4: x[b,j,:] += elu(LN(x1[b,j,:])); normalization folded in.
__global__ void __launch_bounds__(256) k_ln1(const _Float16* __restrict__ a0,
                                             const _Float16* __restrict__ a1,
                                             const float* __restrict__ p0,
                                             const float* __restrict__ p1,
                                             const float* __restrict__ sc,
                                             const float* __restrict__ bi,
                                             float* __restrict__ x){
  int j = blockIdx.x & (NN-1);
  int b = blockIdx.x / NN;
  int c = threadIdx.x;
  int w = c >> 6, l = c & 63;
  int hh = j >> 9;
  int node = ((j & 511) << 2) + w;
  size_t ridx = (size_t)(b*NH + hh)*NN + node;
  float inv = 1.f / (p0[ridx] + p1[ridx]);
  size_t idx = ridx*DK + l;
  float v = ((float)a0[idx] + (float)a1[idx]) * inv;
  __shared__ float red[8];
  float s = v;
  #pragma unroll
  for (int o = 32; o >= 1; o >>= 1) s += __shfl_xor(s, o);
  if (l == 0) red[w] = s;
  __syncthreads();
  float mu = (red[0]+red[1]+red[2]+red[3]) * (1.f/HD);
  float dv = v - mu;
  float q = dv*dv;
  #pragma unroll
  for (int o = 32; o >= 1; o >>= 1) q += __shfl_xor(q, o);
  if (l == 0) red[4+w] = q;
  __syncthreads();
  float var = (red[4]+red[5]+red[6]+red[7]) * (1.f/HD);
  float ln = dv * rsqrtf(var + 1e-5f) * sc[c] + bi[c];
  float el = (ln > 0.f) ? ln : (__expf(ln) - 1.f);
  x[(size_t)blockIdx.x*HD + c] += el;
}

// ---------------------------------------------------------------------------
// K5: out[b,n,d] = LN_64( mean_h att2[b,h,n,d] ), normalization folded in
__global__ void __launch_bounds__(256) k_final(const _Float16* __restrict__ a0,
                                               const _Float16* __restrict__ a1,
                                               const float* __restrict__ p0,
                                               const float* __restrict__ p1,
                                               const float* __restrict__ sc,
                                               const float* __restrict__ bi,
                                               float* __restrict__ out){
  int w = threadIdx.x >> 6; int d = threadIdx.x & 63;
  int bn = blockIdx.x*4 + w;
  int b = bn / NN; int n = bn & (NN-1);
  float v = 0.f;
  #pragma unroll
  for (int hh = 0; hh < NH; ++hh){
    size_t ridx = (size_t)(b*NH + hh)*NN + n;
    float inv = 1.f / (p0[ridx] + p1[ridx]);
    size_t idx = ridx*DK + d;
    v += ((float)a0[idx] + (float)a1[idx]) * inv;
  }
  v *= 0.25f;
  float s = v;
  #pragma unroll
  for (int o = 32; o >= 1; o >>= 1) s += __shfl_xor(s, o);
  float mu = s * (1.f/DK);
  float dv = v - mu;
  float q = dv*dv;
  #pragma unroll
  for (int o = 32; o >= 1; o >>= 1) q += __shfl_xor(q, o);
  float var = q * (1.f/DK);
  float ln = dv * rsqrtf(var + 1e-5f) * sc[d] + bi[d];
  out[(size_t)bn*DK + d] = ln;
}

// ---------------------------------------------------------------------------
extern "C" void kernel_launch(void* const* d_in, const int* in_sizes, int n_in,
                              void* d_out, int out_size, void* d_ws, size_t ws_size,
                              hipStream_t stream){
  const float* nf   = (const float*)d_in[0];
  const int*   adj  = (const int*)d_in[1];
  const float* Wp   = (const float*)d_in[2];
  const float* bp   = (const float*)d_in[3];
  const float* W1   = (const float*)d_in[4];
  const float* a1   = (const float*)d_in[5];
  const float* ln1s = (const float*)d_in[6];
  const float* ln1b = (const float*)d_in[7];
  const float* W2   = (const float*)d_in[8];
  const float* a2   = (const float*)d_in[9];
  const float* ln2s = (const float*)d_in[10];
  const float* ln2b = (const float*)d_in[11];

  float* ws   = (float*)d_ws;
  float* x    = ws;                            // 2,097,152 f32
  _Float16* accF = (_Float16*)(ws + 2097152);  // 2 x 2,097,152 f16
  float* srcb = ws + 3*2097152;                // 32,768
  float* dstb = srcb + 32768;                  // 32,768
  float* psA  = dstb + 32768;                  // 2 x 32,768
  _Float16* hT = (_Float16*)(psA + 2*32768);   // 2,097,152 f16
  u64* maskT  = (u64*)(hT + 2097152);          // 262,144 u64
  _Float16* WTF = (_Float16*)(maskT + 262144); // 131,072 f16 (2 layers)
  _Float16* WpF = WTF + 131072;                // 32,768 f16
  float* aS   = (float*)(WpF + 32768);         // 1024 f32

  _Float16* accH0 = accF;
  _Float16* accH1 = accF + 2097152;
  float* psH0  = psA;
  float* psH1  = psA + 32768;

  k_setup   <<<2064,        256, 0, stream>>>(adj, Wp, W1, a1, W2, a2,
                                              maskT, WTF, WpF, aS);
  k_head4<1><<<BB*NH*NN/64, 256, 0, stream>>>(nf, WpF, WTF,        aS,       bp, x, hT, srcb, dstb);
  k_attn8   <<<BB*NH*NN/16, 256, 0, stream>>>(srcb, dstb, hT, maskT, accF, psA);
  k_ln1     <<<BB*NN,       256, 0, stream>>>(accH0, accH1, psH0, psH1, ln1s, ln1b, x);
  k_head4<0><<<BB*NH*NN/64, 256, 0, stream>>>(x, WpF, WTF + 65536, aS + 512, bp, x, hT, srcb, dstb);
  k_attn8   <<<BB*NH*NN/16, 256, 0, stream>>>(srcb, dstb, hT, maskT, accF, psA);
  k_final   <<<BB*NN/4,     256, 0, stream>>>(accH0, accH1, psH0, psH1, ln2s, ln2b, (float*)d_out);
}

// Round 16
// 118.943 us; speedup vs baseline: 1.0561x; 1.0119x over previous
//
#include <hip/hip_runtime.h>
#include <hip/hip_bf16.h>
#include <hip/hip_fp16.h>

// Shapes (fixed by the reference)
#define BB   4
#define NN   2048
#define FIN  128
#define HD   256
#define NH   4
#define DK   64
#define NEGV (-1000000000.0f)
#define LOG2E 1.4426950408889634f

typedef _Float16 f16x8 __attribute__((ext_vector_type(8)));
typedef _Float16 f16x4 __attribute__((ext_vector_type(4)));
typedef __fp16   h16x2 __attribute__((ext_vector_type(2)));
typedef __fp16   h16x4 __attribute__((ext_vector_type(4)));
typedef __fp16   h16x8 __attribute__((ext_vector_type(8)));
typedef float    f32x16 __attribute__((ext_vector_type(16)));
typedef unsigned long long u64;

// XOR swizzles: flip byte bits 4-6 with row bits (pitch 512B / 256B)
__device__ __forceinline__ int SWZ9(int b){ return b ^ (((b >> 9) & 7) << 4); }
__device__ __forceinline__ int SWZ8(int b){ return b ^ (((b >> 8) & 7) << 4); }

__device__ __forceinline__ float fexp2(float x){
#if __has_builtin(__builtin_amdgcn_exp2f)
  return __builtin_amdgcn_exp2f(x);
#else
  return __exp2f(x);
#endif
}

__device__ __forceinline__ f16x8 pack8(float4 a, float4 b){
  f16x8 r;
  r[0]=(_Float16)a.x; r[1]=(_Float16)a.y; r[2]=(_Float16)a.z; r[3]=(_Float16)a.w;
  r[4]=(_Float16)b.x; r[5]=(_Float16)b.y; r[6]=(_Float16)b.z; r[7]=(_Float16)b.w;
  return r;
}

// ---------------------------------------------------------------------------
// K_setup: blocks [0,2048): int4-wide bitmask pack (maskT[b][mt][n]).
//          blocks [2048,2056): WTF fragment-ordered head weights + aS.
//          blocks [2056,2064): WpF fragment-ordered proj weights.
__global__ void __launch_bounds__(256) k_setup(const int* __restrict__ adj,
                                               const float* __restrict__ Wp,
                                               const float* __restrict__ W1,
                                               const float* __restrict__ a1,
                                               const float* __restrict__ W2,
                                               const float* __restrict__ a2,
                                               u64* __restrict__ maskT,
                                               _Float16* __restrict__ WTF,
                                               _Float16* __restrict__ WpF,
                                               float* __restrict__ aS){
  int bid = blockIdx.x;
  int t = threadIdx.x;
  if (bid < 2048){
    int w = t >> 6, lane = t & 63;
    int row = bid*4 + w;
    int b = row >> 11, n = row & (NN-1);
    const int4* ar = (const int4*)(adj + (size_t)row*NN);
    int g = lane >> 4, q = lane & 15;
    #pragma unroll 2
    for (int step = 0; step < 8; ++step){
      int4 v = ar[step*64 + lane];
      unsigned nib = (unsigned)((v.x!=0) | ((v.y!=0)<<1) | ((v.z!=0)<<2) | ((v.w!=0)<<3));
      unsigned lo = (q < 8) ? (nib << (q*4)) : 0u;
      unsigned hi = (q < 8) ? 0u : (nib << ((q-8)*4));
      #pragma unroll
      for (int off = 1; off < 16; off <<= 1){
        lo |= __shfl_xor(lo, off);
        hi |= __shfl_xor(hi, off);
      }
      if (q == 0) maskT[(size_t)(b*32 + step*4 + g)*NN + n] = ((u64)hi << 32) | lo;
    }
  } else if (bid < 2056){
    int qq = bid - 2048;            // lay*4+hh
    int lay = qq >> 2, hh = qq & 3;
    const float* W = (lay ? W2 : W1) + (size_t)hh*HD*DK;
    const float* a = (lay ? a2 : a1) + (size_t)hh*2*DK;
    _Float16* wf = WTF + (size_t)qq*32*512;     // 32 frags x 512 f16
    int j = t*2;
    int l5 = j >> 4, lh = (j >> 3) & 1, e = j & 7;
    #pragma unroll 4
    for (int f = 0; f < 32; ++f){
      int kk = f >> 1, dh = f & 1;
      wf[f*512 + j]     = (_Float16)W[(kk*16 + lh*8 + e    )*DK + dh*32 + l5];
      wf[f*512 + j + 1] = (_Float16)W[(kk*16 + lh*8 + e + 1)*DK + dh*32 + l5];
    }
    if (t < 128) aS[(size_t)qq*128 + t] = a[t] * LOG2E;
  } else {
    int kk = bid - 2056;            // 0..7 (k-step)
    int j = t*2;
    int l5 = j >> 4, lh = (j >> 3) & 1, e = j & 7;
    #pragma unroll 4
    for (int cs = 0; cs < 8; ++cs){
      WpF[(kk*8 + cs)*512 + j]     = (_Float16)Wp[(kk*16 + lh*8 + e    )*HD + cs*32 + l5];
      WpF[(kk*8 + cs)*512 + j + 1] = (_Float16)Wp[(kk*16 + lh*8 + e + 1)*HD + cs*32 + l5];
    }
  }
}

// ---------------------------------------------------------------------------
// K2: MFMA head projection, proj-fused for layer 1 (unchanged from round 12).
template<int L1>
__global__ void __launch_bounds__(256) k_head4(const float* __restrict__ xin,
                                               const _Float16* __restrict__ WpF,
                                               const _Float16* __restrict__ WTF,
                                               const float* __restrict__ aS,
                                               const float* __restrict__ bp,
                                               float* __restrict__ xout,
                                               _Float16* __restrict__ hT,
                                               float* __restrict__ src,
                                               float* __restrict__ dst){
  int nt = blockIdx.x & 31;
  int bh = blockIdx.x >> 5;
  int b = bh >> 2, hh = bh & 3;
  int n0 = nt * 64;
  int t = threadIdx.x;
  int w = t >> 6, l = t & 63, lh = l >> 5, l5 = l & 31;
  int wr = w >> 1, wc = w & 1;

  __shared__ __align__(16) char sm[50176];  // xs16 [0,32K); nfs [32K,48K); sd [48K,49K)

  if (L1){
    {
      int r = t >> 2, c0 = (t & 3) * 32;
      const float* np = xin + ((size_t)(b*NN) + n0 + r)*FIN + c0;
      #pragma unroll
      for (int u = 0; u < 4; ++u){
        float4 v0 = *(const float4*)&np[u*8];
        float4 v1 = *(const float4*)&np[u*8 + 4];
        *(f16x8*)&sm[32768 + SWZ8(r*256 + (c0 + u*8)*2)] = pack8(v0, v1);
      }
    }
    __syncthreads();
    f32x16 p00 = {}, p01 = {}, p10 = {}, p11 = {};
    #pragma unroll
    for (int kk = 0; kk < 8; ++kk){
      int ab = (kk*16 + lh*8)*2;
      f16x8 A0 = *(const f16x8*)&sm[32768 + SWZ8(l5*256 + ab)];
      f16x8 A1 = *(const f16x8*)&sm[32768 + SWZ8((32 + l5)*256 + ab)];
      const char* bf = (const char*)WpF + (size_t)(kk*8 + w*2)*1024 + l5*32 + lh*16;
      f16x8 B0 = *(const f16x8*)bf;
      f16x8 B1 = *(const f16x8*)(bf + 1024);
      p00 = __builtin_amdgcn_mfma_f32_32x32x16_f16(A0, B0, p00, 0, 0, 0);
      p01 = __builtin_amdgcn_mfma_f32_32x32x16_f16(A0, B1, p01, 0, 0, 0);
      p10 = __builtin_amdgcn_mfma_f32_32x32x16_f16(A1, B0, p10, 0, 0, 0);
      p11 = __builtin_amdgcn_mfma_f32_32x32x16_f16(A1, B1, p11, 0, 0, 0);
    }
    int c0a = w*64 + l5;
    float bp0 = bp[c0a], bp1 = bp[c0a + 32];
    size_t ro = ((size_t)(b*NN) + n0)*HD;
    #pragma unroll
    for (int g = 0; g < 16; ++g){
      int rr = (g & 3) + 8*(g >> 2) + 4*lh;
      float v00 = p00[g] + bp0, v01 = p01[g] + bp1;
      float v10 = p10[g] + bp0, v11 = p11[g] + bp1;
      *(_Float16*)&sm[SWZ9(rr*512 + c0a*2)]             = (_Float16)v00;
      *(_Float16*)&sm[SWZ9(rr*512 + (c0a + 32)*2)]      = (_Float16)v01;
      *(_Float16*)&sm[SWZ9((rr+32)*512 + c0a*2)]        = (_Float16)v10;
      *(_Float16*)&sm[SWZ9((rr+32)*512 + (c0a + 32)*2)] = (_Float16)v11;
      if (hh == 0){
        xout[ro + (size_t)rr*HD + c0a]           = v00;
        xout[ro + (size_t)rr*HD + c0a + 32]      = v01;
        xout[ro + (size_t)(rr+32)*HD + c0a]      = v10;
        xout[ro + (size_t)(rr+32)*HD + c0a + 32] = v11;
      }
    }
    __syncthreads();
  } else {
    int r = t >> 2, ks = (t & 3) * 64;
    const float* xp = &xin[((size_t)(b*NN) + n0 + r)*HD + ks];
    #pragma unroll
    for (int u = 0; u < 8; ++u){
      float4 v0 = *(const float4*)&xp[u*8];
      float4 v1 = *(const float4*)&xp[u*8 + 4];
      *(f16x8*)&sm[SWZ9(r*512 + (ks + u*8)*2)] = pack8(v0, v1);
    }
    __syncthreads();
  }

  // h-MFMA: A = x-tile rows (wr half), B = WTF frags (wc d-half), K=256
  f32x16 hA = {}, hB = {};
  const char* wtb = (const char*)WTF + (size_t)hh*32768 + wc*1024 + l5*32 + lh*16;
  #pragma unroll
  for (int kk = 0; kk < 16; kk += 2){
    int ab0 = (kk*16 + lh*8)*2;
    int ab1 = ((kk+1)*16 + lh*8)*2;
    f16x8 A0 = *(const f16x8*)&sm[SWZ9((wr*32 + l5)*512 + ab0)];
    f16x8 A1 = *(const f16x8*)&sm[SWZ9((wr*32 + l5)*512 + ab1)];
    f16x8 B0 = *(const f16x8*)(wtb + (size_t)kk*2048);
    f16x8 B1 = *(const f16x8*)(wtb + (size_t)(kk+1)*2048);
    hA = __builtin_amdgcn_mfma_f32_32x32x16_f16(A0, B0, hA, 0, 0, 0);
    hB = __builtin_amdgcn_mfma_f32_32x32x16_f16(A1, B1, hB, 0, 0, 0);
  }
  f32x16 acc = hA + hB;

  __syncthreads();   // xs16 dead; overlay ls
  _Float16* ls = (_Float16*)sm;        // [64 d][80 rows pad] f16 = 10240B
  int col = wc*32 + l5;
  float as = aS[(size_t)hh*128 + col];
  float ad = aS[(size_t)hh*128 + 64 + col];
  float* sd = (float*)(sm + 49152);    // [2][2][64] f32
  #pragma unroll
  for (int g = 0; g < 16; ++g){
    int row = wr*32 + (g & 3) + 8*(g >> 2) + 4*lh;
    ls[col*80 + row] = (_Float16)acc[g];
    float sv = acc[g] * as;
    float dv = acc[g] * ad;
    #pragma unroll
    for (int o = 16; o >= 1; o >>= 1){ sv += __shfl_xor(sv, o); dv += __shfl_xor(dv, o); }
    if (l5 == 0){
      sd[wc*64 + row]       = sv;
      sd[128 + wc*64 + row] = dv;
    }
  }
  __syncthreads();
  int dd = t >> 2, part = t & 3;
  f16x8 o0 = *(const f16x8*)&ls[dd*80 + part*16];
  f16x8 o1 = *(const f16x8*)&ls[dd*80 + part*16 + 8];
  int base = part*1024 + (dd >> 5)*512 + (dd & 31)*16;
  _Float16* op = hT + (size_t)bh*131072 + (size_t)nt*4096 + base;
  *(f16x8*)op = o0;
  *(f16x8*)(op + 8) = o1;
  if (t < 64){
    src[bh*NN + n0 + t] = sd[t] + sd[64 + t];
    dst[bh*NN + n0 + t] = sd[128 + t] + sd[192 + t];
  }
}

// ---------------------------------------------------------------------------
// K3: MFMA attention, m-split. Block = 32 rows x 1024 cols (half ms); 4 waves =
// 4 k-chunks. 2-deep prefetch slots PINNED with sched_barrier(0); A-frag packed
// via v_cvt_pkrtz (__fp16 vectors, bit_cast to MFMA operand type).
__global__ void __launch_bounds__(256, 4) k_attn8(const float* __restrict__ src,
                                                  const float* __restrict__ dst,
                                                  const _Float16* __restrict__ hT,
                                                  const u64* __restrict__ maskT,
                                                  _Float16* __restrict__ accB,
                                                  float* __restrict__ psB){
  int ms = blockIdx.x & 1;
  int rb = (blockIdx.x >> 1) & 63;
  int bh = blockIdx.x >> 7;
  int b  = bh >> 2;
  int n0 = rb * 32;
  int t = threadIdx.x;
  int w = t >> 6, l = t & 63;
  int lh = l >> 5, l5 = l & 31;

  __shared__ __align__(16) char smem[9728];    // dstS 4KB in loop; cs 9.2KB epilogue
  __shared__ float rs[4][32];
  __shared__ float red[4];
  float* dstS = (float*)smem;
  float* cs   = (float*)smem;

  {
    const float* dp = dst + bh*NN;
    float4 a = *(const float4*)&dp[t*4];
    float4 bq = *(const float4*)&dp[1024 + t*4];
    float mloc = fmaxf(fmaxf(fmaxf(a.x,a.y), fmaxf(a.z,a.w)),
                       fmaxf(fmaxf(bq.x,bq.y), fmaxf(bq.z,bq.w)));
    *(float4*)&dstS[t*4] = ms ? bq : a;
    #pragma unroll
    for (int o = 32; o >= 1; o >>= 1) mloc = fmaxf(mloc, __shfl_xor(mloc, o));
    if (l == 0) red[w] = mloc;
  }
  __syncthreads();
  float Mbh = fmaxf(fmaxf(red[0], red[1]), fmaxf(red[2], red[3]));
  float srcv = src[bh*NN + n0 + l5];
  float bv = srcv + Mbh;
  float bnd = fmaxf(bv, 0.2f*bv);
  float2 ps2 = make_float2(0.f, 0.f);
  f32x16 acc0 = {}, acc1 = {};

  int kb = w*16 + lh*8;
  const u64* mp = maskT + (size_t)(b*32 + ms*16)*NN + n0 + l5;
  const char* gB0 = (const char*)hT + (size_t)bh*262144 + ms*131072
                    + w*2048 + l5*32 + lh*16;

  // 2-deep prefetch slots (rotation static via full unroll)
  u64 mkS0 = mp[0];
  f16x8 B0S0 = *(const f16x8*)(gB0);
  f16x8 B1S0 = *(const f16x8*)(gB0 + 1024);
  u64 mkS1 = mp[NN];
  f16x8 B0S1 = *(const f16x8*)(gB0 + 8192);
  f16x8 B1S1 = *(const f16x8*)(gB0 + 8192 + 1024);
  __builtin_amdgcn_sched_barrier(0);     // prologue loads pinned before loop

  #pragma unroll
  for (int mt = 0; mt < 16; ++mt){
    // consume slot 0
    u64 mkC = mkS0;
    f16x8 B0C = B0S0, B1C = B1S0;
    // shift slot 1 -> 0, refill slot 1 with tile mt+2
    mkS0 = mkS1; B0S0 = B0S1; B1S0 = B1S1;
    if (mt < 14){
      mkS1 = mp[(size_t)(mt+2)*NN];
      B0S1 = *(const f16x8*)(gB0 + (size_t)(mt+2)*8192);
      B1S1 = *(const f16x8*)(gB0 + (size_t)(mt+2)*8192 + 1024);
    }
    __builtin_amdgcn_sched_barrier(0);   // pin: refill issues BEFORE this iter's compute
    float4 dq0 = *(const float4*)&dstS[mt*64 + kb];
    float4 dq1 = *(const float4*)&dstS[mt*64 + kb + 4];
    unsigned bits = (unsigned)(mkC >> kb) & 0xFFu;
    float dvals[8] = {dq0.x,dq0.y,dq0.z,dq0.w,dq1.x,dq1.y,dq1.z,dq1.w};
    h16x2 hp0, hp1, hp2, hp3;
    {
      float e0 = srcv + dvals[0], e1 = srcv + dvals[1];
      e0 = fmaxf(e0, 0.2f*e0); e1 = fmaxf(e1, 0.2f*e1);
      e0 = (bits & 1u) ? e0 : NEGV;  e1 = (bits & 2u) ? e1 : NEGV;
      float p0 = fexp2(e0 - bnd), p1 = fexp2(e1 - bnd);
      ps2.x += p0; ps2.y += p1;
      hp0 = __builtin_amdgcn_cvt_pkrtz(p0, p1);
    }
    {
      float e0 = srcv + dvals[2], e1 = srcv + dvals[3];
      e0 = fmaxf(e0, 0.2f*e0); e1 = fmaxf(e1, 0.2f*e1);
      e0 = (bits & 4u) ? e0 : NEGV;  e1 = (bits & 8u) ? e1 : NEGV;
      float p0 = fexp2(e0 - bnd), p1 = fexp2(e1 - bnd);
      ps2.x += p0; ps2.y += p1;
      hp1 = __builtin_amdgcn_cvt_pkrtz(p0, p1);
    }
    {
      float e0 = srcv + dvals[4], e1 = srcv + dvals[5];
      e0 = fmaxf(e0, 0.2f*e0); e1 = fmaxf(e1, 0.2f*e1);
      e0 = (bits & 16u) ? e0 : NEGV;  e1 = (bits & 32u) ? e1 : NEGV;
      float p0 = fexp2(e0 - bnd), p1 = fexp2(e1 - bnd);
      ps2.x += p0; ps2.y += p1;
      hp2 = __builtin_amdgcn_cvt_pkrtz(p0, p1);
    }
    {
      float e0 = srcv + dvals[6], e1 = srcv + dvals[7];
      e0 = fmaxf(e0, 0.2f*e0); e1 = fmaxf(e1, 0.2f*e1);
      e0 = (bits & 64u) ? e0 : NEGV;  e1 = (bits & 128u) ? e1 : NEGV;
      float p0 = fexp2(e0 - bnd), p1 = fexp2(e1 - bnd);
      ps2.x += p0; ps2.y += p1;
      hp3 = __builtin_amdgcn_cvt_pkrtz(p0, p1);
    }
    h16x4 lo4 = __builtin_shufflevector(hp0, hp1, 0, 1, 2, 3);
    h16x4 hi4 = __builtin_shufflevector(hp2, hp3, 0, 1, 2, 3);
    h16x8 a8  = __builtin_shufflevector(lo4, hi4, 0, 1, 2, 3, 4, 5, 6, 7);
    f16x8 A   = __builtin_bit_cast(f16x8, a8);
    acc0 = __builtin_amdgcn_mfma_f32_32x32x16_f16(A, B0C, acc0, 0, 0, 0);
    acc1 = __builtin_amdgcn_mfma_f32_32x32x16_f16(A, B1C, acc1, 0, 0, 0);
  }

  float psum = ps2.x + ps2.y;
  psum += __shfl_xor(psum, 32);
  if (l < 32) rs[w][l5] = psum;
  __syncthreads();                       // dstS dead; cs overlay safe
  _Float16* accO = accB + (size_t)ms*2097152;
  float* psO  = psB + (size_t)ms*32768;
  if (t < 32) psO[bh*NN + n0 + t] = rs[0][t] + rs[1][t] + rs[2][t] + rs[3][t];
  // sequential cross-wave combine (fits 9.2KB: 64 lanes x 36 floats)
  #pragma unroll 1
  for (int ww = 1; ww < 4; ++ww){
    if (w == ww){
      float* base = cs + l*36;
      *(f32x16*)(base)      = acc0;
      *(f32x16*)(base + 16) = acc1;
    }
    __syncthreads();
    if (w == 0){
      const float* base = cs + l*36;
      acc0 += *(const f32x16*)(base);
      acc1 += *(const f32x16*)(base + 16);
    }
    __syncthreads();
  }
  if (w == 0){
    #pragma unroll
    for (int g = 0; g < 16; ++g){
      int row = (g & 3) + 8*(g >> 2) + 4*lh;
      size_t o = ((size_t)bh*NN + n0 + row)*DK;
      accO[o + l5]      = (_Float16)acc0[g];
      accO[o + 32 + l5] = (_Float16)acc1[g];
    }
  }
}

// ---------------------------------------------------------------------------
// K4: x[b,j,:] += elu(LN(x1[b,j,:])); normalization folded in.
__global__ void __launch_bounds__(256) k_ln1(const _Float16* __restrict__ a0,
                                             const _Float16* __restrict__ a1,
                                             const float* __restrict__ p0,
                                             const float* __restrict__ p1,
                                             const float* __restrict__ sc,
                                             const float* __restrict__ bi,
                                             float* __restrict__ x){
  int j = blockIdx.x & (NN-1);
  int b = blockIdx.x / NN;
  int c = threadIdx.x;
  int w = c >> 6, l = c & 63;
  int hh = j >> 9;
  int node = ((j & 511) << 2) + w;
  size_t ridx = (size_t)(b*NH + hh)*NN + node;
  float inv = 1.f / (p0[ridx] + p1[ridx]);
  size_t idx = ridx*DK + l;
  float v = ((float)a0[idx] + (float)a1[idx]) * inv;
  __shared__ float red[8];
  float s = v;
  #pragma unroll
  for (int o = 32; o >= 1; o >>= 1) s += __shfl_xor(s, o);
  if (l == 0) red[w] = s;
  __syncthreads();
  float mu = (red[0]+red[1]+red[2]+red[3]) * (1.f/HD);
  float dv = v - mu;
  float q = dv*dv;
  #pragma unroll
  for (int o = 32; o >= 1; o >>= 1) q += __shfl_xor(q, o);
  if (l == 0) red[4+w] = q;
  __syncthreads();
  float var = (red[4]+red[5]+red[6]+red[7]) * (1.f/HD);
  float ln = dv * rsqrtf(var + 1e-5f) * sc[c] + bi[c];
  float el = (ln > 0.f) ? ln : (__expf(ln) - 1.f);
  x[(size_t)blockIdx.x*HD + c] += el;
}

// ---------------------------------------------------------------------------
// K5: out[b,n,d] = LN_64( mean_h att2[b,h,n,d] ), normalization folded in
__global__ void __launch_bounds__(256) k_final(const _Float16* __restrict__ a0,
                                               const _Float16* __restrict__ a1,
                                               const float* __restrict__ p0,
                                               const float* __restrict__ p1,
                                               const float* __restrict__ sc,
                                               const float* __restrict__ bi,
                                               float* __restrict__ out){
  int w = threadIdx.x >> 6; int d = threadIdx.x & 63;
  int bn = blockIdx.x*4 + w;
  int b = bn / NN; int n = bn & (NN-1);
  float v = 0.f;
  #pragma unroll
  for (int hh = 0; hh < NH; ++hh){
    size_t ridx = (size_t)(b*NH + hh)*NN + n;
    float inv = 1.f / (p0[ridx] + p1[ridx]);
    size_t idx = ridx*DK + d;
    v += ((float)a0[idx] + (float)a1[idx]) * inv;
  }
  v *= 0.25f;
  float s = v;
  #pragma unroll
  for (int o = 32; o >= 1; o >>= 1) s += __shfl_xor(s, o);
  float mu = s * (1.f/DK);
  float dv = v - mu;
  float q = dv*dv;
  #pragma unroll
  for (int o = 32; o >= 1; o >>= 1) q += __shfl_xor(q, o);
  float var = q * (1.f/DK);
  float ln = dv * rsqrtf(var + 1e-5f) * sc[d] + bi[d];
  out[(size_t)bn*DK + d] = ln;
}

// ---------------------------------------------------------------------------
extern "C" void kernel_launch(void* const* d_in, const int* in_sizes, int n_in,
                              void* d_out, int out_size, void* d_ws, size_t ws_size,
                              hipStream_t stream){
  const float* nf   = (const float*)d_in[0];
  const int*   adj  = (const int*)d_in[1];
  const float* Wp   = (const float*)d_in[2];
  const float* bp   = (const float*)d_in[3];
  const float* W1   = (const float*)d_in[4];
  const float* a1   = (const float*)d_in[5];
  const float* ln1s = (const float*)d_in[6];
  const float* ln1b = (const float*)d_in[7];
  const float* W2   = (const float*)d_in[8];
  const float* a2   = (const float*)d_in[9];
  const float* ln2s = (const float*)d_in[10];
  const float* ln2b = (const float*)d_in[11];

  float* ws   = (float*)d_ws;
  float* x    = ws;                            // 2,097,152 f32
  _Float16* accF = (_Float16*)(ws + 2097152);  // 2 x 2,097,152 f16
  float* srcb = ws + 3*2097152;                // 32,768
  float* dstb = srcb + 32768;                  // 32,768
  float* psA  = dstb + 32768;                  // 2 x 32,768
  _Float16* hT = (_Float16*)(psA + 2*32768);   // 2,097,152 f16
  u64* maskT  = (u64*)(hT + 2097152);          // 262,144 u64
  _Float16* WTF = (_Float16*)(maskT + 262144); // 131,072 f16 (2 layers)
  _Float16* WpF = WTF + 131072;                // 32,768 f16
  float* aS   = (float*)(WpF + 32768);         // 1024 f32

  _Float16* accH0 = accF;
  _Float16* accH1 = accF + 2097152;
  float* psH0  = psA;
  float* psH1  = psA + 32768;

  k_setup   <<<2064,        256, 0, stream>>>(adj, Wp, W1, a1, W2, a2,
                                              maskT, WTF, WpF, aS);
  k_head4<1><<<BB*NH*NN/64, 256, 0, stream>>>(nf, WpF, WTF,        aS,       bp, x, hT, srcb, dstb);
  k_attn8   <<<BB*NH*NN/16, 256, 0, stream>>>(srcb, dstb, hT, maskT, accF, psA);
  k_ln1     <<<BB*NN,       256, 0, stream>>>(accH0, accH1, psH0, psH1, ln1s, ln1b, x);
  k_head4<0><<<BB*NH*NN/64, 256, 0, stream>>>(x, WpF, WTF + 65536, aS + 512, bp, x, hT, srcb, dstb);
  k_attn8   <<<BB*NH*NN/16, 256, 0, stream>>>(srcb, dstb, hT, maskT, accF, psA);
  k_final   <<<BB*NN/4,     256, 0, stream>>>(accH0, accH1, psH0, psH1, ln2s, ln2b, (float*)d_out);
}